// Round 1
// baseline (6657.230 us; speedup 1.0000x reference)
//
#include <hip/hip_runtime.h>
#include <hip/hip_bf16.h>

// PrototypeKmeansDivergence: B=64, T=512, D=768, L=4, K=6, 20 kmeans iters.
// One block (768 threads = 12 waves) per batch element; exact MT19937
// replication of np.random.RandomState(0) for kmeans++ init.

constexpr int BB = 64;
constexpr int TT = 512;
constexpr int DD = 768;
constexpr int KMAX = 6;
constexpr int KM_ITERS = 20;
constexpr int NT = 768;           // threads per block (12 waves of 64)
constexpr int NWAVES = NT / 64;

// ---- MT19937 (numpy legacy RandomState stream) ----
__device__ __forceinline__ unsigned mt_next(unsigned* mt, int& mti) {
    if (mti >= 624) {
        // single-loop twist with %624 is equivalent to the standard
        // 3-segment version (later indices read already-updated values
        // exactly where the standard algorithm does).
        for (int i = 0; i < 624; ++i) {
            unsigned y = (mt[i] & 0x80000000u) | (mt[(i + 1) % 624] & 0x7fffffffu);
            unsigned v = mt[(i + 397) % 624] ^ (y >> 1);
            if (y & 1u) v ^= 0x9908b0dfu;
            mt[i] = v;
        }
        mti = 0;
    }
    unsigned y = mt[mti++];
    y ^= y >> 11;
    y ^= (y << 7) & 0x9d2c5680u;
    y ^= (y << 15) & 0xefc60000u;
    y ^= y >> 18;
    return y;
}

__global__ __launch_bounds__(NT) void pkd_main(
        const float* __restrict__ feats, const int* __restrict__ dlens,
        const int* __restrict__ labels, const float* __restrict__ kprob,
        float* __restrict__ losses) {
    __shared__ double s_cent[KMAX][DD];      // 36864 B (fp64 centers)
    __shared__ float  s_proto[4][DD];        // 12288 B
    __shared__ double s_d2[TT];              // 4096 B
    __shared__ double s_cdf[TT];             // 4096 B
    __shared__ unsigned s_mt[624];           // 2496 B
    __shared__ unsigned char s_assign[TT];   // 512 B
    __shared__ unsigned char s_lab[TT];      // 512 B
    __shared__ int s_cnt[8];
    __shared__ int s_lcnt[4];
    __shared__ int s_i[4];                   // 0: max label, 1: k, 2: chosen idx
    __shared__ double s_cost[4][KMAX];

    const int bi  = blockIdx.x;
    const int tid = threadIdx.x;
    const int wv  = tid >> 6;
    const int ln  = tid & 63;
    const int n   = dlens[bi];
    const float* __restrict__ F = feats + (size_t)bi * TT * DD;
    int mti = 624;   // only meaningful in thread 0

    for (int i = tid; i < KMAX * DD; i += NT) (&s_cent[0][0])[i] = 0.0;
    if (tid < 8) s_cnt[tid] = 0;
    if (tid < 4) s_lcnt[tid] = 0;
    if (tid == 0) s_i[0] = 0;
    __syncthreads();

    // ---- labels: cache, max, histogram ----
    for (int p = tid; p < n; p += NT) {
        int l = labels[bi * TT + p];
        s_lab[p] = (unsigned char)l;
        atomicMax(&s_i[0], l);
        atomicAdd(&s_lcnt[l], 1);
    }
    __syncthreads();
    const int lr = s_i[0] + 1;   // label_range

    // ---- prototypes (per-label mean, fp64 accumulate -> fp32) ----
    {
        double p0 = 0, p1 = 0, p2 = 0, p3 = 0;
        for (int p = 0; p < n; ++p) {
            float x = F[(size_t)p * DD + tid];
            switch (s_lab[p]) {          // uniform across block -> no divergence
                case 0: p0 += x; break;
                case 1: p1 += x; break;
                case 2: p2 += x; break;
                default: p3 += x; break;
            }
        }
        s_proto[0][tid] = (float)(p0 / (double)s_lcnt[0]);
        s_proto[1][tid] = (float)(p1 / (double)s_lcnt[1]);
        s_proto[2][tid] = (float)(p2 / (double)s_lcnt[2]);
        s_proto[3][tid] = (float)(p3 / (double)s_lcnt[3]);
    }

    // ---- k = argmax(k_prob)+1 ; MT seed ; randint(n) ----
    if (tid == 0) {
        const float* kp = kprob + bi * KMAX;
        int bj = 0; float bv = kp[0];
        for (int j = 1; j < KMAX; ++j) if (kp[j] > bv) { bv = kp[j]; bj = j; }
        s_i[1] = bj + 1;
        unsigned s = 0u;
        for (int i = 0; i < 624; ++i) {
            s_mt[i] = s;
            s = 1812433253u * (s ^ (s >> 30)) + (unsigned)(i + 1);
        }
        // legacy randint: 32-bit masked rejection
        unsigned rngv = (unsigned)(n - 1);
        unsigned mask = rngv;
        mask |= mask >> 1; mask |= mask >> 2; mask |= mask >> 4;
        mask |= mask >> 8; mask |= mask >> 16;
        unsigned val;
        do { val = mt_next(s_mt, mti) & mask; } while (val > rngv);
        s_i[2] = (int)val;
    }
    __syncthreads();
    const int kk = s_i[1];

    // center 0 = X[idx0]
    s_cent[0][tid] = (double)F[(size_t)s_i[2] * DD + tid];
    __syncthreads();

    // wave-cooperative squared distance of point p to center c (all lanes get sum)
    auto dist2_all = [&](const double* __restrict__ c, int p) -> double {
        const float* row = F + (size_t)p * DD;
        double acc = 0.0;
        #pragma unroll
        for (int i = 0; i < DD / 64; ++i) {
            int d = ln + (i << 6);
            double df = (double)row[d] - c[d];
            acc += df * df;
        }
        #pragma unroll
        for (int off = 32; off; off >>= 1) acc += __shfl_xor(acc, off, 64);
        return acc;
    };

    for (int p = wv; p < n; p += NWAVES) {
        double a = dist2_all(s_cent[0], p);
        if (ln == 0) s_d2[p] = a;
    }
    __syncthreads();

    // ---- kmeans++ remaining centers ----
    for (int j = 1; j < kk; ++j) {
        if (tid == 0) {
            double S = 0.0;
            for (int p = 0; p < n; ++p) S += s_d2[p];
            if (S < 1e-12) S = 1e-12;
            double cum = 0.0;
            for (int p = 0; p < n; ++p) { cum += s_d2[p] / S; s_cdf[p] = cum; }
            double last = s_cdf[n - 1];
            // legacy random_sample(): two 32-bit draws
            unsigned ua = mt_next(s_mt, mti) >> 5;
            unsigned ub = mt_next(s_mt, mti) >> 6;
            double u = ((double)ua * 67108864.0 + (double)ub) / 9007199254740992.0;
            int idx = n - 1;
            for (int p = 0; p < n; ++p) {
                if (s_cdf[p] / last > u) { idx = p; break; }   // searchsorted 'right'
            }
            s_i[2] = idx;
        }
        __syncthreads();
        s_cent[j][tid] = (double)F[(size_t)s_i[2] * DD + tid];
        __syncthreads();
        for (int p = wv; p < n; p += NWAVES) {
            double a = dist2_all(s_cent[j], p);
            if (ln == 0) s_d2[p] = fmin(s_d2[p], a);
        }
        __syncthreads();
    }

    // ---- Lloyd iterations ----
    for (int it = 0; it < KM_ITERS; ++it) {
        // assignment
        for (int p = wv; p < n; p += NWAVES) {
            const float* row = F + (size_t)p * DD;
            double a0 = 0, a1 = 0, a2 = 0, a3 = 0, a4 = 0, a5 = 0;
            #pragma unroll
            for (int i = 0; i < DD / 64; ++i) {
                int d = ln + (i << 6);
                double x = (double)row[d];
                double t;
                t = x - s_cent[0][d]; a0 += t * t;
                t = x - s_cent[1][d]; a1 += t * t;
                t = x - s_cent[2][d]; a2 += t * t;
                t = x - s_cent[3][d]; a3 += t * t;
                t = x - s_cent[4][d]; a4 += t * t;
                t = x - s_cent[5][d]; a5 += t * t;
            }
            #pragma unroll
            for (int off = 32; off; off >>= 1) {
                a0 += __shfl_xor(a0, off, 64);
                a1 += __shfl_xor(a1, off, 64);
                a2 += __shfl_xor(a2, off, 64);
                a3 += __shfl_xor(a3, off, 64);
                a4 += __shfl_xor(a4, off, 64);
                a5 += __shfl_xor(a5, off, 64);
            }
            if (ln == 0) {
                int bj = 0; double bv = a0;
                if (kk > 1 && a1 < bv) { bv = a1; bj = 1; }
                if (kk > 2 && a2 < bv) { bv = a2; bj = 2; }
                if (kk > 3 && a3 < bv) { bv = a3; bj = 3; }
                if (kk > 4 && a4 < bv) { bv = a4; bj = 4; }
                if (kk > 5 && a5 < bv) { bv = a5; bj = 5; }
                s_assign[p] = (unsigned char)bj;
            }
        }
        __syncthreads();
        if (tid < 8) s_cnt[tid] = 0;
        __syncthreads();
        for (int p = tid; p < n; p += NT) atomicAdd(&s_cnt[s_assign[p]], 1);
        __syncthreads();
        // update (dim-owner: one dim per thread)
        double u0 = 0, u1 = 0, u2 = 0, u3 = 0, u4 = 0, u5 = 0;
        for (int p = 0; p < n; ++p) {
            float x = F[(size_t)p * DD + tid];
            switch (s_assign[p]) {       // uniform -> no divergence
                case 0: u0 += x; break;
                case 1: u1 += x; break;
                case 2: u2 += x; break;
                case 3: u3 += x; break;
                case 4: u4 += x; break;
                default: u5 += x; break;
            }
        }
        __syncthreads();
        if (s_cnt[0] > 0) s_cent[0][tid] = u0 / (double)s_cnt[0];
        if (s_cnt[1] > 0) s_cent[1][tid] = u1 / (double)s_cnt[1];
        if (s_cnt[2] > 0) s_cent[2][tid] = u2 / (double)s_cnt[2];
        if (s_cnt[3] > 0) s_cent[3][tid] = u3 / (double)s_cnt[3];
        if (s_cnt[4] > 0) s_cent[4][tid] = u4 / (double)s_cnt[4];
        if (s_cnt[5] > 0) s_cent[5][tid] = u5 / (double)s_cnt[5];
        __syncthreads();
    }

    // ---- cost matrix (fp32 centers, like centers.astype(np.float32)) ----
    if (tid < lr * kk) {
        int r = tid / kk, j = tid - (tid / kk) * kk;
        double acc = 0.0;
        for (int d = 0; d < DD; ++d) {
            float cf = (float)s_cent[j][d];
            double df = (double)s_proto[r][d] - (double)cf;
            acc += df * df;
        }
        s_cost[r][j] = sqrt(acc);
    }
    __syncthreads();

    // ---- exhaustive LSA (min over injective maps, smaller side -> larger) ----
    if (tid == 0) {
        const int sdim = (lr <= kk) ? lr : kk;
        const int mdim = (lr <= kk) ? kk : lr;
        const bool tr = (lr > kk);
        auto CC = [&](int i, int j) -> double {
            return tr ? s_cost[j][i] : s_cost[i][j];
        };
        double best = 1e300;
        for (int c0 = 0; c0 < mdim; ++c0) {
            double v0 = CC(0, c0);
            if (sdim == 1) { if (v0 < best) best = v0; continue; }
            for (int c1 = 0; c1 < mdim; ++c1) {
                if (c1 == c0) continue;
                double v1 = v0 + CC(1, c1);
                if (sdim == 2) { if (v1 < best) best = v1; continue; }
                for (int c2 = 0; c2 < mdim; ++c2) {
                    if (c2 == c0 || c2 == c1) continue;
                    double v2 = v1 + CC(2, c2);
                    if (sdim == 3) { if (v2 < best) best = v2; continue; }
                    for (int c3 = 0; c3 < mdim; ++c3) {
                        if (c3 == c0 || c3 == c1 || c3 == c2) continue;
                        double v3 = v2 + CC(3, c3);
                        if (v3 < best) best = v3;
                    }
                }
            }
        }
        double meand = best / (double)sdim;
        double kp = (double)kprob[bi * KMAX + (lr - 1)];
        losses[bi] = (float)(0.5 * meand - 0.5 * log(kp));
    }
}

__global__ void pkd_reduce(const float* __restrict__ losses, float* __restrict__ out) {
    if (blockIdx.x == 0 && threadIdx.x == 0) {
        double s = 0.0;
        for (int i = 0; i < BB; ++i) s += (double)losses[i];
        out[0] = (float)(s / (double)BB);
    }
}

extern "C" void kernel_launch(void* const* d_in, const int* in_sizes, int n_in,
                              void* d_out, int out_size, void* d_ws, size_t ws_size,
                              hipStream_t stream) {
    const float* feats  = (const float*)d_in[0];
    const int*   dlens  = (const int*)d_in[1];
    const int*   labels = (const int*)d_in[2];
    const float* kprob  = (const float*)d_in[3];
    float* losses = (float*)d_ws;

    pkd_main<<<BB, NT, 0, stream>>>(feats, dlens, labels, kprob, losses);
    pkd_reduce<<<1, 64, 0, stream>>>(losses, (float*)d_out);
}

// Round 2
// 4345.982 us; speedup vs baseline: 1.5318x; 1.5318x over previous
//
#include <hip/hip_runtime.h>
#include <hip/hip_bf16.h>

// PrototypeKmeansDivergence: B=64, T=512, D=768, L=4, K=6, 20 kmeans iters.
// One block (768 thr = 12 waves) per batch. LDS-tiled streaming, fp32 distance
// math (fp64 reference RNG stream kept bit-exact), DPP wave reductions.

constexpr int BB = 64;
constexpr int TT = 512;
constexpr int DD = 768;
constexpr int KMAX = 6;
constexpr int KM_ITERS = 20;
constexpr int NT = 768;
constexpr int NWAVES = 12;
constexpr int TILE_P = 16;
constexpr int SMEM_BYTES = 139264;

// ---- MT19937 (numpy legacy RandomState stream; validated bit-exact in R1) ----
__device__ __forceinline__ unsigned mt_next(unsigned* mt, int& mti) {
    if (mti >= 624) {
        for (int i = 0; i < 624; ++i) {
            unsigned y = (mt[i] & 0x80000000u) | (mt[(i + 1) % 624] & 0x7fffffffu);
            unsigned v = mt[(i + 397) % 624] ^ (y >> 1);
            if (y & 1u) v ^= 0x9908b0dfu;
            mt[i] = v;
        }
        mti = 0;
    }
    unsigned y = mt[mti++];
    y ^= y >> 11;
    y ^= (y << 7) & 0x9d2c5680u;
    y ^= (y << 15) & 0xefc60000u;
    y ^= y >> 18;
    return y;
}

// full-wave (64 lane) fp32 sum: 4 DPP adds (VALU pipe) + 2 shuffles
__device__ __forceinline__ float wsum64(float v) {
    int t;
    t = __builtin_amdgcn_update_dpp(0, __float_as_int(v), 0xB1, 0xF, 0xF, true);  // quad_perm xor1
    v += __int_as_float(t);
    t = __builtin_amdgcn_update_dpp(0, __float_as_int(v), 0x4E, 0xF, 0xF, true);  // quad_perm xor2
    v += __int_as_float(t);
    t = __builtin_amdgcn_update_dpp(0, __float_as_int(v), 0x141, 0xF, 0xF, true); // row_half_mirror (xor7)
    v += __int_as_float(t);
    t = __builtin_amdgcn_update_dpp(0, __float_as_int(v), 0x140, 0xF, 0xF, true); // row_mirror (xor15)
    v += __int_as_float(t);
    v += __shfl_xor(v, 16, 64);
    v += __shfl_xor(v, 32, 64);
    return v;
}

__device__ __forceinline__ double dsum64(double v) {
    #pragma unroll
    for (int off = 1; off < 64; off <<= 1) v += __shfl_xor(v, off, 64);
    return v;
}

__global__ __launch_bounds__(NT, 3) void pkd_main(
        const float* __restrict__ feats, const int* __restrict__ dlens,
        const int* __restrict__ labels, const float* __restrict__ kprob,
        float* __restrict__ losses) {
    extern __shared__ char smem[];
    float*   s_tile  = (float*)smem;                   // [2][16][768]  98304 B
    float*   s_cent  = (float*)(smem + 98304);         // [6][768]      18432 B
    float*   s_proto = (float*)(smem + 116736);        // [4][768]      12288 B
    double*  s_cdf   = (double*)(smem + 129024);       // [512]          4096 B
    float*   s_d2    = (float*)(smem + 133120);        // [512]          2048 B
    unsigned* s_mt   = (unsigned*)(smem + 135168);     // [624]          2496 B
    unsigned char* s_lab = (unsigned char*)(smem + 137664); // [512]
    unsigned char* s_asn = (unsigned char*)(smem + 138176); // [512]
    double*  s_red   = (double*)(smem + 138688);       // [16]
    double*  s_cost  = (double*)(smem + 138816);       // [24]
    int*     s_int   = (int*)(smem + 139008);          // [20]: 0-7 cnt, 8-11 lcnt, 12 maxlab, 13 kk, 14 idx

    const int bi  = blockIdx.x;
    const int tid = threadIdx.x;
    const int wv  = tid >> 6;
    const int ln  = tid & 63;
    const int n   = dlens[bi];
    const int nt  = (n + TILE_P - 1) / TILE_P;
    const float* __restrict__ F = feats + (size_t)bi * TT * DD;
    int mti = 624;  // thread 0 only

    if (tid < 20) s_int[tid] = 0;
    __syncthreads();

    // ---- labels: cache bytes, max, histogram ----
    for (int p = tid; p < n; p += NT) {
        int l = labels[bi * TT + p];
        s_lab[p] = (unsigned char)l;
        atomicMax(&s_int[12], l);
        atomicAdd(&s_int[8 + l], 1);
    }
    if (tid == 0) {
        const float* kp = kprob + bi * KMAX;
        int bj = 0; float bv = kp[0];
        for (int j = 1; j < KMAX; ++j) if (kp[j] > bv) { bv = kp[j]; bj = j; }
        s_int[13] = bj + 1;
        unsigned s = 0u;
        for (int i = 0; i < 624; ++i) {
            s_mt[i] = s;
            s = 1812433253u * (s ^ (s >> 30)) + (unsigned)(i + 1);
        }
        unsigned rngv = (unsigned)(n - 1);
        unsigned mask = rngv;
        mask |= mask >> 1; mask |= mask >> 2; mask |= mask >> 4;
        mask |= mask >> 8; mask |= mask >> 16;
        unsigned val;
        do { val = mt_next(s_mt, mti) & mask; } while (val > rngv);
        s_int[14] = (int)val;
    }
    __syncthreads();
    const int kk = s_int[13];
    const int lr = s_int[12] + 1;

    // stage center 0 = X[idx0] (fp32)
    s_cent[tid] = F[(size_t)s_int[14] * DD + tid];
    __syncthreads();

    // ================= kmeans++ init passes =================
    double pp0 = 0, pp1 = 0, pp2 = 0, pp3 = 0;  // prototype accumulators (pass 0)
    for (int j = 0; j < kk; ++j) {
        if (j > 0) {
            // ---- selection of center j (parallel scan; RNG stream exact) ----
            if (tid == 0) {
                unsigned ua = mt_next(s_mt, mti) >> 5;
                unsigned ub = mt_next(s_mt, mti) >> 6;
                s_red[10] = ((double)ua * 67108864.0 + (double)ub) * (1.0 / 9007199254740992.0);
                s_int[14] = n - 1;  // fallback
            }
            if (tid < 512) {
                double x = (tid < n) ? (double)s_d2[tid] : 0.0;
                double w = dsum64(x);
                if (ln == 0) s_red[wv] = w;
            }
            __syncthreads();
            if (tid == 0) {
                double S = 0; for (int i = 0; i < 8; ++i) S += s_red[i];
                if (S < 1e-12) S = 1e-12;
                s_red[8] = 1.0 / S;
            }
            __syncthreads();
            if (tid < 512) s_cdf[tid] = (tid < n) ? (double)s_d2[tid] * s_red[8] : 0.0;
            __syncthreads();
            for (int st = 1; st < 512; st <<= 1) {
                double v = (tid < 512 && tid >= st) ? s_cdf[tid - st] : 0.0;
                __syncthreads();
                if (tid < 512) s_cdf[tid] += v;
                __syncthreads();
            }
            if (tid == 0) s_red[9] = 1.0 / s_cdf[n - 1];
            __syncthreads();
            if (tid < n) {
                double il = s_red[9], u = s_red[10];
                double right = s_cdf[tid] * il;
                double left  = tid ? s_cdf[tid - 1] * il : 0.0;
                if (right > u && left <= u) s_int[14] = tid;  // searchsorted 'right'
            }
            __syncthreads();
            s_cent[j * DD + tid] = F[(size_t)s_int[14] * DD + tid];
            __syncthreads();
        }
        // ---- tiled pass: d2 vs center j (+ prototypes fused on pass 0) ----
        float4 cj[3];
        #pragma unroll
        for (int i = 0; i < 3; ++i) cj[i] = *(const float4*)(s_cent + j * DD + 4 * ln + 256 * i);

        float4 stg[4];
        #pragma unroll
        for (int q = 0; q < 4; ++q) stg[q] = *(const float4*)(F + 4 * (tid + NT * q));
        #pragma unroll
        for (int q = 0; q < 4; ++q) {
            int c = tid + NT * q;
            *(float4*)(s_tile + (c / 192) * DD + 4 * (c % 192)) = stg[q];
        }
        __syncthreads();
        for (int t = 0; t < nt; ++t) {
            const int cur = t & 1, nxt = cur ^ 1;
            const float* tb = s_tile + cur * (TILE_P * DD);
            if (t + 1 < nt) {
                size_t base = (size_t)(t + 1) * TILE_P * DD;
                #pragma unroll
                for (int q = 0; q < 4; ++q) stg[q] = *(const float4*)(F + base + 4 * (tid + NT * q));
            }
            for (int pl = wv; pl < TILE_P; pl += NWAVES) {
                int p = t * TILE_P + pl;
                if (p < n) {
                    const float* row = tb + pl * DD;
                    float a = 0.f;
                    #pragma unroll
                    for (int i = 0; i < 3; ++i) {
                        float4 x = *(const float4*)(row + 4 * ln + 256 * i);
                        float d;
                        d = x.x - cj[i].x; a = fmaf(d, d, a);
                        d = x.y - cj[i].y; a = fmaf(d, d, a);
                        d = x.z - cj[i].z; a = fmaf(d, d, a);
                        d = x.w - cj[i].w; a = fmaf(d, d, a);
                    }
                    a = wsum64(a);
                    if (ln == 0) s_d2[p] = (j == 0) ? a : fminf(s_d2[p], a);
                }
            }
            if (j == 0) {
                const uint4 lw4 = *(const uint4*)(s_lab + t * 16);
                const unsigned lw0 = lw4.x, lw1 = lw4.y, lw2 = lw4.z, lw3 = lw4.w;
                const int m = min(TILE_P, n - t * TILE_P);
                #pragma unroll
                for (int i = 0; i < TILE_P; ++i) {
                    if (i < m) {
                        unsigned w = (i < 4) ? lw0 : (i < 8) ? lw1 : (i < 12) ? lw2 : lw3;
                        int l = (w >> ((i & 3) * 8)) & 255;
                        float x = tb[i * DD + tid];
                        switch (l) {
                            case 0: pp0 += x; break;
                            case 1: pp1 += x; break;
                            case 2: pp2 += x; break;
                            default: pp3 += x;
                        }
                    }
                }
            }
            if (t + 1 < nt) {
                #pragma unroll
                for (int q = 0; q < 4; ++q) {
                    int c = tid + NT * q;
                    *(float4*)(s_tile + nxt * (TILE_P * DD) + (c / 192) * DD + 4 * (c % 192)) = stg[q];
                }
            }
            __syncthreads();
        }
    }
    // prototype write (fp64 accum -> fp32)
    s_proto[0 * DD + tid] = (float)(pp0 / (double)s_int[8]);
    s_proto[1 * DD + tid] = (float)(pp1 / (double)s_int[9]);
    s_proto[2 * DD + tid] = (float)(pp2 / (double)s_int[10]);
    s_proto[3 * DD + tid] = (float)(pp3 / (double)s_int[11]);
    __syncthreads();

    // ================= Lloyd iterations =================
    for (int it = 0; it < KM_ITERS; ++it) {
        float4 creg[6][3];
        #pragma unroll
        for (int c = 0; c < 6; ++c)
            #pragma unroll
            for (int i = 0; i < 3; ++i)
                creg[c][i] = *(const float4*)(s_cent + c * DD + 4 * ln + 256 * i);
        if (tid < 8) s_int[tid] = 0;
        double u0 = 0, u1 = 0, u2 = 0, u3 = 0, u4 = 0, u5 = 0;

        float4 stg[4];
        #pragma unroll
        for (int q = 0; q < 4; ++q) stg[q] = *(const float4*)(F + 4 * (tid + NT * q));
        #pragma unroll
        for (int q = 0; q < 4; ++q) {
            int c = tid + NT * q;
            *(float4*)(s_tile + (c / 192) * DD + 4 * (c % 192)) = stg[q];
        }
        __syncthreads();

        for (int t = 0; t < nt; ++t) {
            const int cur = t & 1, nxt = cur ^ 1;
            const float* tb = s_tile + cur * (TILE_P * DD);
            if (t + 1 < nt) {
                size_t base = (size_t)(t + 1) * TILE_P * DD;
                #pragma unroll
                for (int q = 0; q < 4; ++q) stg[q] = *(const float4*)(F + base + 4 * (tid + NT * q));
            }
            // ---- ASSIGN (wave-per-point, centers in regs) ----
            for (int pl = wv; pl < TILE_P; pl += NWAVES) {
                int p = t * TILE_P + pl;
                if (p < n) {
                    const float* row = tb + pl * DD;
                    float a0 = 0, a1 = 0, a2 = 0, a3 = 0, a4 = 0, a5 = 0;
                    #pragma unroll
                    for (int i = 0; i < 3; ++i) {
                        float4 x = *(const float4*)(row + 4 * ln + 256 * i);
                        float d;
                        d = x.x - creg[0][i].x; a0 = fmaf(d, d, a0);
                        d = x.y - creg[0][i].y; a0 = fmaf(d, d, a0);
                        d = x.z - creg[0][i].z; a0 = fmaf(d, d, a0);
                        d = x.w - creg[0][i].w; a0 = fmaf(d, d, a0);
                        d = x.x - creg[1][i].x; a1 = fmaf(d, d, a1);
                        d = x.y - creg[1][i].y; a1 = fmaf(d, d, a1);
                        d = x.z - creg[1][i].z; a1 = fmaf(d, d, a1);
                        d = x.w - creg[1][i].w; a1 = fmaf(d, d, a1);
                        d = x.x - creg[2][i].x; a2 = fmaf(d, d, a2);
                        d = x.y - creg[2][i].y; a2 = fmaf(d, d, a2);
                        d = x.z - creg[2][i].z; a2 = fmaf(d, d, a2);
                        d = x.w - creg[2][i].w; a2 = fmaf(d, d, a2);
                        d = x.x - creg[3][i].x; a3 = fmaf(d, d, a3);
                        d = x.y - creg[3][i].y; a3 = fmaf(d, d, a3);
                        d = x.z - creg[3][i].z; a3 = fmaf(d, d, a3);
                        d = x.w - creg[3][i].w; a3 = fmaf(d, d, a3);
                        d = x.x - creg[4][i].x; a4 = fmaf(d, d, a4);
                        d = x.y - creg[4][i].y; a4 = fmaf(d, d, a4);
                        d = x.z - creg[4][i].z; a4 = fmaf(d, d, a4);
                        d = x.w - creg[4][i].w; a4 = fmaf(d, d, a4);
                        d = x.x - creg[5][i].x; a5 = fmaf(d, d, a5);
                        d = x.y - creg[5][i].y; a5 = fmaf(d, d, a5);
                        d = x.z - creg[5][i].z; a5 = fmaf(d, d, a5);
                        d = x.w - creg[5][i].w; a5 = fmaf(d, d, a5);
                    }
                    a0 = wsum64(a0); a1 = wsum64(a1); a2 = wsum64(a2);
                    a3 = wsum64(a3); a4 = wsum64(a4); a5 = wsum64(a5);
                    int bj = 0; float bv = a0;
                    if (kk > 1 && a1 < bv) { bv = a1; bj = 1; }
                    if (kk > 2 && a2 < bv) { bv = a2; bj = 2; }
                    if (kk > 3 && a3 < bv) { bv = a3; bj = 3; }
                    if (kk > 4 && a4 < bv) { bv = a4; bj = 4; }
                    if (kk > 5 && a5 < bv) { bv = a5; bj = 5; }
                    if (ln == 0) { s_asn[p] = (unsigned char)bj; atomicAdd(&s_int[bj], 1); }
                }
            }
            __syncthreads();  // assignments visible
            if (t + 1 < nt) {
                #pragma unroll
                for (int q = 0; q < 4; ++q) {
                    int c = tid + NT * q;
                    *(float4*)(s_tile + nxt * (TILE_P * DD) + (c / 192) * DD + 4 * (c % 192)) = stg[q];
                }
            }
            // ---- UPDATE (dim-owner column reads, fp64 accumulate) ----
            {
                const uint4 aw4 = *(const uint4*)(s_asn + t * 16);
                const unsigned aw0 = aw4.x, aw1 = aw4.y, aw2 = aw4.z, aw3 = aw4.w;
                const int m = min(TILE_P, n - t * TILE_P);
                #pragma unroll
                for (int i = 0; i < TILE_P; ++i) {
                    if (i < m) {
                        unsigned w = (i < 4) ? aw0 : (i < 8) ? aw1 : (i < 12) ? aw2 : aw3;
                        int c = (w >> ((i & 3) * 8)) & 255;
                        float x = tb[i * DD + tid];
                        switch (c) {
                            case 0: u0 += x; break;
                            case 1: u1 += x; break;
                            case 2: u2 += x; break;
                            case 3: u3 += x; break;
                            case 4: u4 += x; break;
                            default: u5 += x;
                        }
                    }
                }
            }
            __syncthreads();  // update done + next tile visible
        }
        {
            int c0 = s_int[0], c1 = s_int[1], c2 = s_int[2],
                c3 = s_int[3], c4 = s_int[4], c5 = s_int[5];
            if (c0 > 0) s_cent[0 * DD + tid] = (float)(u0 / (double)c0);
            if (c1 > 0) s_cent[1 * DD + tid] = (float)(u1 / (double)c1);
            if (c2 > 0) s_cent[2 * DD + tid] = (float)(u2 / (double)c2);
            if (c3 > 0) s_cent[3 * DD + tid] = (float)(u3 / (double)c3);
            if (c4 > 0) s_cent[4 * DD + tid] = (float)(u4 / (double)c4);
            if (c5 > 0) s_cent[5 * DD + tid] = (float)(u5 / (double)c5);
        }
        __syncthreads();
    }

    // ---- cost matrix: wave-per-(proto,center) pair ----
    for (int pr = wv; pr < lr * kk; pr += NWAVES) {
        int r = pr / kk, c = pr - (pr / kk) * kk;
        double acc = 0.0;
        #pragma unroll
        for (int i = 0; i < 12; ++i) {
            int d = ln + 64 * i;
            double df = (double)s_proto[r * DD + d] - (double)s_cent[c * DD + d];
            acc += df * df;
        }
        acc = dsum64(acc);
        if (ln == 0) s_cost[r * KMAX + c] = sqrt(acc);
    }
    __syncthreads();

    // ---- exhaustive LSA + loss ----
    if (tid == 0) {
        const int sdim = (lr <= kk) ? lr : kk;
        const int mdim = (lr <= kk) ? kk : lr;
        const bool tr = (lr > kk);
        auto CC = [&](int i, int j) -> double {
            return tr ? s_cost[j * KMAX + i] : s_cost[i * KMAX + j];
        };
        double best = 1e300;
        for (int c0 = 0; c0 < mdim; ++c0) {
            double v0 = CC(0, c0);
            if (sdim == 1) { if (v0 < best) best = v0; continue; }
            for (int c1 = 0; c1 < mdim; ++c1) {
                if (c1 == c0) continue;
                double v1 = v0 + CC(1, c1);
                if (sdim == 2) { if (v1 < best) best = v1; continue; }
                for (int c2 = 0; c2 < mdim; ++c2) {
                    if (c2 == c0 || c2 == c1) continue;
                    double v2 = v1 + CC(2, c2);
                    if (sdim == 3) { if (v2 < best) best = v2; continue; }
                    for (int c3 = 0; c3 < mdim; ++c3) {
                        if (c3 == c0 || c3 == c1 || c3 == c2) continue;
                        double v3 = v2 + CC(3, c3);
                        if (v3 < best) best = v3;
                    }
                }
            }
        }
        double meand = best / (double)sdim;
        double kp = (double)kprob[bi * KMAX + (lr - 1)];
        losses[bi] = (float)(0.5 * meand - 0.5 * log(kp));
    }
}

__global__ void pkd_reduce(const float* __restrict__ losses, float* __restrict__ out) {
    if (blockIdx.x == 0 && threadIdx.x == 0) {
        double s = 0.0;
        for (int i = 0; i < BB; ++i) s += (double)losses[i];
        out[0] = (float)(s / (double)BB);
    }
}

extern "C" void kernel_launch(void* const* d_in, const int* in_sizes, int n_in,
                              void* d_out, int out_size, void* d_ws, size_t ws_size,
                              hipStream_t stream) {
    const float* feats  = (const float*)d_in[0];
    const int*   dlens  = (const int*)d_in[1];
    const int*   labels = (const int*)d_in[2];
    const float* kprob  = (const float*)d_in[3];
    float* losses = (float*)d_ws;

    (void)hipFuncSetAttribute((const void*)pkd_main,
                              hipFuncAttributeMaxDynamicSharedMemorySize, SMEM_BYTES);
    pkd_main<<<BB, NT, SMEM_BYTES, stream>>>(feats, dlens, labels, kprob, losses);
    pkd_reduce<<<1, 64, 0, stream>>>(losses, (float*)d_out);
}

// Round 3
// 2974.121 us; speedup vs baseline: 2.2384x; 1.4613x over previous
//
#include <hip/hip_runtime.h>
#include <hip/hip_bf16.h>

// PrototypeKmeansDivergence: B=64, T=512, D=768, L=4, K=6, 20 kmeans iters.
// R3: 4 blocks per batch (256 blocks, 1 per CU) under cooperative launch.
// Per-batch spin barriers; deterministic fp32 partials + fp64 combine.
// MT19937 stream (sub0/tid0 only) identical to R1/R2 (validated bit-exact).

constexpr int BB = 64;
constexpr int TT = 512;
constexpr int DD = 768;
constexpr int KMAX = 6;
constexpr int KM_ITERS = 20;
constexpr int NT = 768;
constexpr int NWAVES = 12;
constexpr int TILE_P = 16;
constexpr int NSUB = 4;          // blocks per batch
constexpr int PTS = 128;         // points per sub-block slice
constexpr int SMEM_BYTES = 137344;

// ---- workspace layout (bytes); total ~8.02 MB ----
constexpr size_t WS_BAR  = 0;        // [64] int, stride 64 B (zeroed by memsetAsync)
constexpr size_t WS_IDX  = 4096;     // [64] int  (chosen center index)
constexpr size_t WS_CNT  = 4608;     // [64][4][8] int
constexpr size_t WS_D2   = 16384;    // [64][512] f32
constexpr size_t WS_PP   = 147456;   // [64][4][4][768] f32 (proto partials)
constexpr size_t WS_PS   = 3293184;  // [64][4][6][768] f32 (center partials)
constexpr size_t WS_LOSS = 8011776;  // [64] f32

// ---- MT19937 (numpy legacy RandomState stream) ----
__device__ __forceinline__ unsigned mt_next(unsigned* mt, int& mti) {
    if (mti >= 624) {
        for (int i = 0; i < 624; ++i) {
            unsigned y = (mt[i] & 0x80000000u) | (mt[(i + 1) % 624] & 0x7fffffffu);
            unsigned v = mt[(i + 397) % 624] ^ (y >> 1);
            if (y & 1u) v ^= 0x9908b0dfu;
            mt[i] = v;
        }
        mti = 0;
    }
    unsigned y = mt[mti++];
    y ^= y >> 11;
    y ^= (y << 7) & 0x9d2c5680u;
    y ^= (y << 15) & 0xefc60000u;
    y ^= y >> 18;
    return y;
}

__device__ __forceinline__ float wsum64(float v) {
    int t;
    t = __builtin_amdgcn_update_dpp(0, __float_as_int(v), 0xB1, 0xF, 0xF, true);
    v += __int_as_float(t);
    t = __builtin_amdgcn_update_dpp(0, __float_as_int(v), 0x4E, 0xF, 0xF, true);
    v += __int_as_float(t);
    t = __builtin_amdgcn_update_dpp(0, __float_as_int(v), 0x141, 0xF, 0xF, true);
    v += __int_as_float(t);
    t = __builtin_amdgcn_update_dpp(0, __float_as_int(v), 0x140, 0xF, 0xF, true);
    v += __int_as_float(t);
    v += __shfl_xor(v, 16, 64);
    v += __shfl_xor(v, 32, 64);
    return v;
}

__device__ __forceinline__ double dsum64(double v) {
    #pragma unroll
    for (int off = 1; off < 64; off <<= 1) v += __shfl_xor(v, off, 64);
    return v;
}

__global__ __launch_bounds__(NT, 1) void pkd_main(
        const float* __restrict__ feats, const int* __restrict__ dlens,
        const int* __restrict__ labels, const float* __restrict__ kprob,
        char* __restrict__ ws) {
    extern __shared__ char smem[];
    float*   s_tile  = (float*)smem;                        // [2][16][768] 98304
    float*   s_cent  = (float*)(smem + 98304);              // [6][768]     18432
    float*   s_proto = (float*)(smem + 116736);             // [4][768]     12288
    double*  s_cdf   = (double*)(smem + 129024);            // [512]         4096
    float*   s_d2    = (float*)(smem + 133120);             // [128] local    512
    unsigned* s_mt   = (unsigned*)(smem + 133632);          // [624]         2496
    unsigned char* s_lab = (unsigned char*)(smem + 136128); // [512]
    unsigned char* s_asn = (unsigned char*)(smem + 136640); // [128]
    double*  s_red   = (double*)(smem + 136768);            // [16]
    double*  s_cost  = (double*)(smem + 136896);            // [24]
    int*     s_int   = (int*)(smem + 137088);               // [64]

    int* g_bar  = (int*)(ws + WS_BAR);
    int* g_idx  = (int*)(ws + WS_IDX);
    int* g_cnt  = (int*)(ws + WS_CNT);
    float* g_d2 = (float*)(ws + WS_D2);
    float* g_pp = (float*)(ws + WS_PP);
    float* g_ps = (float*)(ws + WS_PS);
    float* g_loss = (float*)(ws + WS_LOSS);

    const int bid = blockIdx.x;
    const int bi  = bid & 63;        // batch
    const int sub = bid >> 6;        // slice id 0..3 (same XCD for all 4: +64 ≡ mod 8)
    const int tid = threadIdx.x;
    const int wv  = tid >> 6;
    const int ln  = tid & 63;
    const int n   = dlens[bi];
    const int p0g = sub * PTS;                       // global point base of slice
    const int nb  = max(0, min(PTS, n - p0g));       // slice length
    const int ntl = (nb + TILE_P - 1) / TILE_P;
    const float* __restrict__ F = feats + (size_t)bi * TT * DD;
    int* bar = g_bar + bi * 16;
    int gen = 0;
    int mti = 624;   // thread 0 of sub 0 only

    auto BAR = [&]() {
        __syncthreads();
        if (tid == 0) {
            gen += NSUB;
            __hip_atomic_fetch_add(bar, 1, __ATOMIC_RELEASE, __HIP_MEMORY_SCOPE_AGENT);
            while (__hip_atomic_load(bar, __ATOMIC_ACQUIRE, __HIP_MEMORY_SCOPE_AGENT) < gen)
                __builtin_amdgcn_s_sleep(2);
        }
        __syncthreads();
    };

    if (tid < 64) s_int[tid] = 0;
    __syncthreads();

    // ---- labels (full range, redundant per block): cache, max, histogram ----
    for (int p = tid; p < n; p += NT) {
        int l = labels[bi * TT + p];
        s_lab[p] = (unsigned char)l;
        atomicMax(&s_int[12], l);
        atomicAdd(&s_int[8 + l], 1);
    }
    if (tid == 0) {
        const float* kp = kprob + bi * KMAX;
        int bj = 0; float bv = kp[0];
        for (int j = 1; j < KMAX; ++j) if (kp[j] > bv) { bv = kp[j]; bj = j; }
        s_int[13] = bj + 1;
        if (sub == 0) {
            unsigned s = 0u;
            for (int i = 0; i < 624; ++i) {
                s_mt[i] = s;
                s = 1812433253u * (s ^ (s >> 30)) + (unsigned)(i + 1);
            }
            unsigned rngv = (unsigned)(n - 1);
            unsigned mask = rngv;
            mask |= mask >> 1; mask |= mask >> 2; mask |= mask >> 4;
            mask |= mask >> 8; mask |= mask >> 16;
            unsigned val;
            do { val = mt_next(s_mt, mti) & mask; } while (val > rngv);
            g_idx[bi] = (int)val;
        }
    }
    __syncthreads();
    const int kk = s_int[13];
    const int lr = s_int[12] + 1;
    BAR();   // idx0 visible

    s_cent[tid] = F[(size_t)g_idx[bi] * DD + tid];
    __syncthreads();

    // ================= kmeans++ init (slice passes + sub0 selection) =========
    double pp0 = 0, pp1 = 0, pp2 = 0, pp3 = 0;
    for (int j = 0; j < kk; ++j) {
        if (j > 0) {
            if (sub == 0) {
                if (tid == 0) {
                    unsigned ua = mt_next(s_mt, mti) >> 5;
                    unsigned ub = mt_next(s_mt, mti) >> 6;
                    s_red[10] = ((double)ua * 67108864.0 + (double)ub) * (1.0 / 9007199254740992.0);
                    s_int[14] = n - 1;
                }
                if (tid < 512) {
                    double x = (tid < n) ? (double)g_d2[bi * TT + tid] : 0.0;
                    double w = dsum64(x);
                    if (ln == 0) s_red[wv] = w;
                }
                __syncthreads();
                if (tid == 0) {
                    double S = 0; for (int i = 0; i < 8; ++i) S += s_red[i];
                    if (S < 1e-12) S = 1e-12;
                    s_red[8] = 1.0 / S;
                }
                __syncthreads();
                if (tid < 512)
                    s_cdf[tid] = (tid < n) ? (double)g_d2[bi * TT + tid] * s_red[8] : 0.0;
                __syncthreads();
                for (int st = 1; st < 512; st <<= 1) {
                    double v = (tid < 512 && tid >= st) ? s_cdf[tid - st] : 0.0;
                    __syncthreads();
                    if (tid < 512) s_cdf[tid] += v;
                    __syncthreads();
                }
                if (tid == 0) s_red[9] = 1.0 / s_cdf[n - 1];
                __syncthreads();
                if (tid < n) {
                    double il = s_red[9], u = s_red[10];
                    double right = s_cdf[tid] * il;
                    double left  = tid ? s_cdf[tid - 1] * il : 0.0;
                    if (right > u && left <= u) s_int[14] = tid;
                }
                __syncthreads();
                if (tid == 0) g_idx[bi] = s_int[14];
            }
            BAR();   // idx j visible
            s_cent[j * DD + tid] = F[(size_t)g_idx[bi] * DD + tid];
            __syncthreads();
        }
        // ---- tiled slice pass: d2 vs center j (+ proto partials on j==0) ----
        float4 cj[3];
        #pragma unroll
        for (int i = 0; i < 3; ++i) cj[i] = *(const float4*)(s_cent + j * DD + 4 * ln + 256 * i);

        float4 stg[4];
        if (ntl > 0) {
            size_t base = (size_t)p0g * DD;
            #pragma unroll
            for (int q = 0; q < 4; ++q) stg[q] = *(const float4*)(F + base + 4 * (tid + NT * q));
            #pragma unroll
            for (int q = 0; q < 4; ++q) {
                int c = tid + NT * q;
                *(float4*)(s_tile + (c / 192) * DD + 4 * (c % 192)) = stg[q];
            }
        }
        __syncthreads();
        for (int t = 0; t < ntl; ++t) {
            const int cur = t & 1, nxt = cur ^ 1;
            const float* tb = s_tile + cur * (TILE_P * DD);
            if (t + 1 < ntl) {
                size_t base = (size_t)(p0g + (t + 1) * TILE_P) * DD;
                #pragma unroll
                for (int q = 0; q < 4; ++q) stg[q] = *(const float4*)(F + base + 4 * (tid + NT * q));
            }
            for (int pl = wv; pl < TILE_P; pl += NWAVES) {
                int lp = t * TILE_P + pl;
                if (lp < nb) {
                    const float* row = tb + pl * DD;
                    float a = 0.f;
                    #pragma unroll
                    for (int i = 0; i < 3; ++i) {
                        float4 x = *(const float4*)(row + 4 * ln + 256 * i);
                        float d;
                        d = x.x - cj[i].x; a = fmaf(d, d, a);
                        d = x.y - cj[i].y; a = fmaf(d, d, a);
                        d = x.z - cj[i].z; a = fmaf(d, d, a);
                        d = x.w - cj[i].w; a = fmaf(d, d, a);
                    }
                    a = wsum64(a);
                    if (ln == 0) s_d2[lp] = (j == 0) ? a : fminf(s_d2[lp], a);
                }
            }
            if (j == 0) {
                const uint4 lw4 = *(const uint4*)(s_lab + p0g + t * 16);
                const unsigned lw0 = lw4.x, lw1 = lw4.y, lw2 = lw4.z, lw3 = lw4.w;
                const int m = min(TILE_P, nb - t * TILE_P);
                #pragma unroll
                for (int i = 0; i < TILE_P; ++i) {
                    if (i < m) {
                        unsigned w = (i < 4) ? lw0 : (i < 8) ? lw1 : (i < 12) ? lw2 : lw3;
                        int l = (w >> ((i & 3) * 8)) & 255;
                        float x = tb[i * DD + tid];
                        switch (l) {
                            case 0: pp0 += x; break;
                            case 1: pp1 += x; break;
                            case 2: pp2 += x; break;
                            default: pp3 += x;
                        }
                    }
                }
            }
            if (t + 1 < ntl) {
                #pragma unroll
                for (int q = 0; q < 4; ++q) {
                    int c = tid + NT * q;
                    *(float4*)(s_tile + nxt * (TILE_P * DD) + (c / 192) * DD + 4 * (c % 192)) = stg[q];
                }
            }
            __syncthreads();
        }
        // publish d2 slice (+ proto partials once)
        if (tid < nb) g_d2[bi * TT + p0g + tid] = s_d2[tid];
        if (j == 0) {
            size_t pb = (((size_t)bi * NSUB + sub) * 4) * DD + tid;
            g_pp[pb + 0 * DD] = (float)pp0;
            g_pp[pb + 1 * DD] = (float)pp1;
            g_pp[pb + 2 * DD] = (float)pp2;
            g_pp[pb + 3 * DD] = (float)pp3;
        }
        BAR();   // d2 (and partials) visible
    }

    // ================= Lloyd iterations =================
    for (int it = 0; it < KM_ITERS; ++it) {
        float4 creg[6][3];
        #pragma unroll
        for (int c = 0; c < 6; ++c)
            #pragma unroll
            for (int i = 0; i < 3; ++i)
                creg[c][i] = *(const float4*)(s_cent + c * DD + 4 * ln + 256 * i);
        if (tid < 8) s_int[tid] = 0;
        double u0 = 0, u1 = 0, u2 = 0, u3 = 0, u4 = 0, u5 = 0;

        float4 stg[4];
        if (ntl > 0) {
            size_t base = (size_t)p0g * DD;
            #pragma unroll
            for (int q = 0; q < 4; ++q) stg[q] = *(const float4*)(F + base + 4 * (tid + NT * q));
            #pragma unroll
            for (int q = 0; q < 4; ++q) {
                int c = tid + NT * q;
                *(float4*)(s_tile + (c / 192) * DD + 4 * (c % 192)) = stg[q];
            }
        }
        __syncthreads();

        for (int t = 0; t < ntl; ++t) {
            const int cur = t & 1, nxt = cur ^ 1;
            const float* tb = s_tile + cur * (TILE_P * DD);
            if (t + 1 < ntl) {
                size_t base = (size_t)(p0g + (t + 1) * TILE_P) * DD;
                #pragma unroll
                for (int q = 0; q < 4; ++q) stg[q] = *(const float4*)(F + base + 4 * (tid + NT * q));
            }
            // ---- ASSIGN ----
            for (int pl = wv; pl < TILE_P; pl += NWAVES) {
                int lp = t * TILE_P + pl;
                if (lp < nb) {
                    const float* row = tb + pl * DD;
                    float a0 = 0, a1 = 0, a2 = 0, a3 = 0, a4 = 0, a5 = 0;
                    #pragma unroll
                    for (int i = 0; i < 3; ++i) {
                        float4 x = *(const float4*)(row + 4 * ln + 256 * i);
                        float d;
                        d = x.x - creg[0][i].x; a0 = fmaf(d, d, a0);
                        d = x.y - creg[0][i].y; a0 = fmaf(d, d, a0);
                        d = x.z - creg[0][i].z; a0 = fmaf(d, d, a0);
                        d = x.w - creg[0][i].w; a0 = fmaf(d, d, a0);
                        d = x.x - creg[1][i].x; a1 = fmaf(d, d, a1);
                        d = x.y - creg[1][i].y; a1 = fmaf(d, d, a1);
                        d = x.z - creg[1][i].z; a1 = fmaf(d, d, a1);
                        d = x.w - creg[1][i].w; a1 = fmaf(d, d, a1);
                        d = x.x - creg[2][i].x; a2 = fmaf(d, d, a2);
                        d = x.y - creg[2][i].y; a2 = fmaf(d, d, a2);
                        d = x.z - creg[2][i].z; a2 = fmaf(d, d, a2);
                        d = x.w - creg[2][i].w; a2 = fmaf(d, d, a2);
                        d = x.x - creg[3][i].x; a3 = fmaf(d, d, a3);
                        d = x.y - creg[3][i].y; a3 = fmaf(d, d, a3);
                        d = x.z - creg[3][i].z; a3 = fmaf(d, d, a3);
                        d = x.w - creg[3][i].w; a3 = fmaf(d, d, a3);
                        d = x.x - creg[4][i].x; a4 = fmaf(d, d, a4);
                        d = x.y - creg[4][i].y; a4 = fmaf(d, d, a4);
                        d = x.z - creg[4][i].z; a4 = fmaf(d, d, a4);
                        d = x.w - creg[4][i].w; a4 = fmaf(d, d, a4);
                        d = x.x - creg[5][i].x; a5 = fmaf(d, d, a5);
                        d = x.y - creg[5][i].y; a5 = fmaf(d, d, a5);
                        d = x.z - creg[5][i].z; a5 = fmaf(d, d, a5);
                        d = x.w - creg[5][i].w; a5 = fmaf(d, d, a5);
                    }
                    a0 = wsum64(a0); a1 = wsum64(a1); a2 = wsum64(a2);
                    a3 = wsum64(a3); a4 = wsum64(a4); a5 = wsum64(a5);
                    int bj = 0; float bv = a0;
                    if (kk > 1 && a1 < bv) { bv = a1; bj = 1; }
                    if (kk > 2 && a2 < bv) { bv = a2; bj = 2; }
                    if (kk > 3 && a3 < bv) { bv = a3; bj = 3; }
                    if (kk > 4 && a4 < bv) { bv = a4; bj = 4; }
                    if (kk > 5 && a5 < bv) { bv = a5; bj = 5; }
                    if (ln == 0) { s_asn[lp] = (unsigned char)bj; atomicAdd(&s_int[bj], 1); }
                }
            }
            __syncthreads();
            if (t + 1 < ntl) {
                #pragma unroll
                for (int q = 0; q < 4; ++q) {
                    int c = tid + NT * q;
                    *(float4*)(s_tile + nxt * (TILE_P * DD) + (c / 192) * DD + 4 * (c % 192)) = stg[q];
                }
            }
            // ---- UPDATE (dim-owner) ----
            {
                const uint4 aw4 = *(const uint4*)(s_asn + t * 16);
                const unsigned aw0 = aw4.x, aw1 = aw4.y, aw2 = aw4.z, aw3 = aw4.w;
                const int m = min(TILE_P, nb - t * TILE_P);
                #pragma unroll
                for (int i = 0; i < TILE_P; ++i) {
                    if (i < m) {
                        unsigned w = (i < 4) ? aw0 : (i < 8) ? aw1 : (i < 12) ? aw2 : aw3;
                        int c = (w >> ((i & 3) * 8)) & 255;
                        float x = tb[i * DD + tid];
                        switch (c) {
                            case 0: u0 += x; break;
                            case 1: u1 += x; break;
                            case 2: u2 += x; break;
                            case 3: u3 += x; break;
                            case 4: u4 += x; break;
                            default: u5 += x;
                        }
                    }
                }
            }
            __syncthreads();
        }
        // publish partials
        {
            size_t pb = (((size_t)bi * NSUB + sub) * 6) * DD + tid;
            g_ps[pb + 0 * DD] = (float)u0;
            g_ps[pb + 1 * DD] = (float)u1;
            g_ps[pb + 2 * DD] = (float)u2;
            g_ps[pb + 3 * DD] = (float)u3;
            g_ps[pb + 4 * DD] = (float)u4;
            g_ps[pb + 5 * DD] = (float)u5;
        }
        if (tid < 8) g_cnt[((size_t)bi * NSUB + sub) * 8 + tid] = s_int[tid];
        BAR();   // partials visible
        // deterministic combine (every block, identical arithmetic)
        if (tid < 32) s_int[32 + tid] = g_cnt[((size_t)bi * NSUB + (tid >> 3)) * 8 + (tid & 7)];
        __syncthreads();
        #pragma unroll
        for (int c = 0; c < 6; ++c) {
            int cc = s_int[32 + c] + s_int[40 + c] + s_int[48 + c] + s_int[56 + c];
            size_t pb = ((size_t)bi * NSUB * 6 + c) * DD + tid;
            double sv = (double)g_ps[pb]
                      + (double)g_ps[pb + 6 * DD]
                      + (double)g_ps[pb + 12 * DD]
                      + (double)g_ps[pb + 18 * DD];
            if (cc > 0) s_cent[c * DD + tid] = (float)(sv / (double)cc);
        }
        __syncthreads();
        BAR();   // partials consumed; safe to overwrite next iter
    }

    // ================= epilogue (sub 0 only) =================
    if (sub == 0) {
        // combine prototype partials (fixed order, fp64)
        #pragma unroll
        for (int l = 0; l < 4; ++l) {
            size_t pb = ((size_t)bi * NSUB * 4 + l) * DD + tid;
            double sv = (double)g_pp[pb]
                      + (double)g_pp[pb + 4 * DD]
                      + (double)g_pp[pb + 8 * DD]
                      + (double)g_pp[pb + 12 * DD];
            s_proto[l * DD + tid] = (float)(sv / (double)s_int[8 + l]);
        }
        __syncthreads();
        for (int pr = wv; pr < lr * kk; pr += NWAVES) {
            int r = pr / kk, c = pr - (pr / kk) * kk;
            double acc = 0.0;
            #pragma unroll
            for (int i = 0; i < 12; ++i) {
                int d = ln + 64 * i;
                double df = (double)s_proto[r * DD + d] - (double)s_cent[c * DD + d];
                acc += df * df;
            }
            acc = dsum64(acc);
            if (ln == 0) s_cost[r * KMAX + c] = sqrt(acc);
        }
        __syncthreads();
        if (tid == 0) {
            const int sdim = (lr <= kk) ? lr : kk;
            const int mdim = (lr <= kk) ? kk : lr;
            const bool tr = (lr > kk);
            auto CC = [&](int i, int j) -> double {
                return tr ? s_cost[j * KMAX + i] : s_cost[i * KMAX + j];
            };
            double best = 1e300;
            for (int c0 = 0; c0 < mdim; ++c0) {
                double v0 = CC(0, c0);
                if (sdim == 1) { if (v0 < best) best = v0; continue; }
                for (int c1 = 0; c1 < mdim; ++c1) {
                    if (c1 == c0) continue;
                    double v1 = v0 + CC(1, c1);
                    if (sdim == 2) { if (v1 < best) best = v1; continue; }
                    for (int c2 = 0; c2 < mdim; ++c2) {
                        if (c2 == c0 || c2 == c1) continue;
                        double v2 = v1 + CC(2, c2);
                        if (sdim == 3) { if (v2 < best) best = v2; continue; }
                        for (int c3 = 0; c3 < mdim; ++c3) {
                            if (c3 == c0 || c3 == c1 || c3 == c2) continue;
                            double v3 = v2 + CC(3, c3);
                            if (v3 < best) best = v3;
                        }
                    }
                }
            }
            double meand = best / (double)sdim;
            double kp = (double)kprob[bi * KMAX + (lr - 1)];
            g_loss[bi] = (float)(0.5 * meand - 0.5 * log(kp));
        }
    }
}

__global__ void pkd_reduce(const float* __restrict__ losses, float* __restrict__ out) {
    if (blockIdx.x == 0 && threadIdx.x == 0) {
        double s = 0.0;
        for (int i = 0; i < BB; ++i) s += (double)losses[i];
        out[0] = (float)(s / (double)BB);
    }
}

extern "C" void kernel_launch(void* const* d_in, const int* in_sizes, int n_in,
                              void* d_out, int out_size, void* d_ws, size_t ws_size,
                              hipStream_t stream) {
    const float* feats  = (const float*)d_in[0];
    const int*   dlens  = (const int*)d_in[1];
    const int*   labels = (const int*)d_in[2];
    const float* kprob  = (const float*)d_in[3];
    char* wsp = (char*)d_ws;

    hipMemsetAsync(d_ws, 0, 4096, stream);   // zero barrier counters
    (void)hipFuncSetAttribute((const void*)pkd_main,
                              hipFuncAttributeMaxDynamicSharedMemorySize, SMEM_BYTES);
    void* args[5] = {(void*)&feats, (void*)&dlens, (void*)&labels,
                     (void*)&kprob, (void*)&wsp};
    hipLaunchCooperativeKernel((const void*)pkd_main, dim3(BB * NSUB), dim3(NT),
                               args, SMEM_BYTES, stream);
    pkd_reduce<<<1, 64, 0, stream>>>((const float*)(wsp + WS_LOSS), (float*)d_out);
}

// Round 4
// 1495.728 us; speedup vs baseline: 4.4508x; 1.9884x over previous
//
#include <hip/hip_runtime.h>
#include <hip/hip_bf16.h>

// PrototypeKmeansDivergence: B=64, T=512, D=768, L=4, K=6, 20 kmeans iters.
// R4: 4 blocks/batch cooperative; ALL cross-block data via device-scope
// relaxed UNCACHED atomics (no acq/rel fences -> no L2 flushes); relaxed
// spin barriers; replicated MT19937 + selection (no idx exchange);
// double-buffered Lloyd partials -> 1 barrier per iteration.

constexpr int BB = 64;
constexpr int TT = 512;
constexpr int DD = 768;
constexpr int KMAX = 6;
constexpr int KM_ITERS = 20;
constexpr int NT = 768;
constexpr int NWAVES = 12;
constexpr int TILE_P = 16;
constexpr int NSUB = 4;
constexpr int PTS = 128;
constexpr int SMEM_BYTES = 139392;

// ---- workspace layout (bytes) ----
constexpr size_t WS_BAR  = 0;          // [64] int, stride 64 B (memset to 0)
constexpr size_t WS_LOSS = 4096;       // [64] f32
constexpr size_t WS_PP   = 4608;       // [64][4][4][768] f32 = 3145728
constexpr size_t WS_CNT  = 3150336;    // [1|2][64][4][8] int
constexpr size_t CNT_HALF = (size_t)BB * NSUB * 8;       // ints
constexpr size_t D2_HALF  = (size_t)BB * TT;             // floats
constexpr size_t PS_HALF  = (size_t)BB * NSUB * 6 * DD;  // floats
constexpr size_t WS_END_DBUF = 12866048;

// ---- MT19937 (numpy legacy RandomState; validated bit-exact R1-R3) ----
__device__ __forceinline__ unsigned mt_next(unsigned* mt, int& mti) {
    if (mti >= 624) {
        for (int i = 0; i < 624; ++i) {
            unsigned y = (mt[i] & 0x80000000u) | (mt[(i + 1) % 624] & 0x7fffffffu);
            unsigned v = mt[(i + 397) % 624] ^ (y >> 1);
            if (y & 1u) v ^= 0x9908b0dfu;
            mt[i] = v;
        }
        mti = 0;
    }
    unsigned y = mt[mti++];
    y ^= y >> 11;
    y ^= (y << 7) & 0x9d2c5680u;
    y ^= (y << 15) & 0xefc60000u;
    y ^= y >> 18;
    return y;
}

// device-scope uncached access (relaxed; bypasses non-coherent XCD L2)
__device__ __forceinline__ void ustoref(float* p, float v) {
    __hip_atomic_store(p, v, __ATOMIC_RELAXED, __HIP_MEMORY_SCOPE_AGENT);
}
__device__ __forceinline__ float uloadf(const float* p) {
    return __hip_atomic_load(p, __ATOMIC_RELAXED, __HIP_MEMORY_SCOPE_AGENT);
}
__device__ __forceinline__ void ustorei(int* p, int v) {
    __hip_atomic_store(p, v, __ATOMIC_RELAXED, __HIP_MEMORY_SCOPE_AGENT);
}
__device__ __forceinline__ int uloadi(const int* p) {
    return __hip_atomic_load(p, __ATOMIC_RELAXED, __HIP_MEMORY_SCOPE_AGENT);
}

__device__ __forceinline__ float wsum64(float v) {
    int t;
    t = __builtin_amdgcn_update_dpp(0, __float_as_int(v), 0xB1, 0xF, 0xF, true);
    v += __int_as_float(t);
    t = __builtin_amdgcn_update_dpp(0, __float_as_int(v), 0x4E, 0xF, 0xF, true);
    v += __int_as_float(t);
    t = __builtin_amdgcn_update_dpp(0, __float_as_int(v), 0x141, 0xF, 0xF, true);
    v += __int_as_float(t);
    t = __builtin_amdgcn_update_dpp(0, __float_as_int(v), 0x140, 0xF, 0xF, true);
    v += __int_as_float(t);
    v += __shfl_xor(v, 16, 64);
    v += __shfl_xor(v, 32, 64);
    return v;
}

__device__ __forceinline__ double dsum64(double v) {
    #pragma unroll
    for (int off = 1; off < 64; off <<= 1) v += __shfl_xor(v, off, 64);
    return v;
}

__global__ __launch_bounds__(NT, 1) void pkd_main(
        const float* __restrict__ feats, const int* __restrict__ dlens,
        const int* __restrict__ labels, const float* __restrict__ kprob,
        char* __restrict__ ws, int dbuf) {
    extern __shared__ char smem[];
    float*   s_tile  = (float*)smem;                        // [2][16][768] 98304
    float*   s_cent  = (float*)(smem + 98304);              // [6][768]     18432
    float*   s_proto = (float*)(smem + 116736);             // [4][768]     12288
    double*  s_cdf   = (double*)(smem + 129024);            // [512]         4096
    float*   s_d2    = (float*)(smem + 133120);             // [128]          512
    unsigned* s_mt   = (unsigned*)(smem + 133632);          // [624]         2496
    unsigned char* s_lab = (unsigned char*)(smem + 136128); // [512]
    unsigned char* s_asn = (unsigned char*)(smem + 136640); // [128]
    double*  s_red   = (double*)(smem + 136768);            // [16]
    double*  s_cost  = (double*)(smem + 136896);            // [24]
    int*     s_int   = (int*)(smem + 137088);               // [64]
    float*   s_g2    = (float*)(smem + 137344);             // [512]         2048

    int*   g_bar  = (int*)(ws + WS_BAR);
    float* g_loss = (float*)(ws + WS_LOSS);
    float* g_pp   = (float*)(ws + WS_PP);
    int*   g_cnt  = (int*)(ws + WS_CNT);
    float* g_d2   = (float*)(ws + (dbuf ? 3166720 : 3158528));
    float* g_ps   = (float*)(ws + (dbuf ? 3428864 : 3289600));

    const int bid = blockIdx.x;
    const int bi  = bid & 63;
    const int sub = bid >> 6;
    const int tid = threadIdx.x;
    const int wv  = tid >> 6;
    const int ln  = tid & 63;
    const int n   = dlens[bi];
    const int p0g = sub * PTS;
    const int nb  = max(0, min(PTS, n - p0g));
    const int ntl = (nb + TILE_P - 1) / TILE_P;
    const float* __restrict__ F = feats + (size_t)bi * TT * DD;
    int* bar = g_bar + bi * 16;
    int gen = 0;
    int mti = 624;   // thread 0 of every block (replicated stream)

    // relaxed barrier: __syncthreads() drains vmcnt for every wave first,
    // so all published uncached stores are at the coherence point before
    // the counter add is issued. No cache-maintenance fences.
    auto BAR = [&]() {
        __syncthreads();
        if (tid == 0) {
            gen += NSUB;
            __hip_atomic_fetch_add(bar, 1, __ATOMIC_RELAXED, __HIP_MEMORY_SCOPE_AGENT);
            while (__hip_atomic_load(bar, __ATOMIC_RELAXED, __HIP_MEMORY_SCOPE_AGENT) < gen)
                __builtin_amdgcn_s_sleep(4);
        }
        __syncthreads();
    };

    if (tid < 64) s_int[tid] = 0;
    __syncthreads();

    // ---- labels: cache bytes, max, histogram (replicated per block) ----
    for (int p = tid; p < n; p += NT) {
        int l = labels[bi * TT + p];
        s_lab[p] = (unsigned char)l;
        atomicMax(&s_int[12], l);
        atomicAdd(&s_int[8 + l], 1);
    }
    if (tid == 0) {
        const float* kp = kprob + bi * KMAX;
        int bj = 0; float bv = kp[0];
        for (int j = 1; j < KMAX; ++j) if (kp[j] > bv) { bv = kp[j]; bj = j; }
        s_int[13] = bj + 1;
        unsigned s = 0u;
        for (int i = 0; i < 624; ++i) {
            s_mt[i] = s;
            s = 1812433253u * (s ^ (s >> 30)) + (unsigned)(i + 1);
        }
        unsigned rngv = (unsigned)(n - 1);
        unsigned mask = rngv;
        mask |= mask >> 1; mask |= mask >> 2; mask |= mask >> 4;
        mask |= mask >> 8; mask |= mask >> 16;
        unsigned val;
        do { val = mt_next(s_mt, mti) & mask; } while (val > rngv);
        s_int[14] = (int)val;
    }
    __syncthreads();
    const int kk = s_int[13];
    const int lr = s_int[12] + 1;

    s_cent[tid] = F[(size_t)s_int[14] * DD + tid];
    __syncthreads();

    // ================= kmeans++ init =================
    double pp0 = 0, pp1 = 0, pp2 = 0, pp3 = 0;
    for (int j = 0; j < kk; ++j) {
        if (j > 0) {
            // ---- replicated selection of center j (deterministic) ----
            const int pjr = dbuf ? ((j - 1) & 1) : 0;
            if (tid < 512)
                s_g2[tid] = (tid < n) ? uloadf(&g_d2[(size_t)pjr * D2_HALF + bi * TT + tid]) : 0.f;
            if (tid == 0) {
                unsigned ua = mt_next(s_mt, mti) >> 5;
                unsigned ub = mt_next(s_mt, mti) >> 6;
                s_red[10] = ((double)ua * 67108864.0 + (double)ub) * (1.0 / 9007199254740992.0);
                s_int[14] = n - 1;
            }
            __syncthreads();
            if (tid < 512) {
                double w = dsum64((double)s_g2[tid]);
                if (ln == 0) s_red[wv] = w;
            }
            __syncthreads();
            if (tid == 0) {
                double S = 0; for (int i = 0; i < 8; ++i) S += s_red[i];
                if (S < 1e-12) S = 1e-12;
                s_red[8] = 1.0 / S;
            }
            __syncthreads();
            if (tid < 512) s_cdf[tid] = (tid < n) ? (double)s_g2[tid] * s_red[8] : 0.0;
            __syncthreads();
            for (int st = 1; st < 512; st <<= 1) {
                double v = (tid < 512 && tid >= st) ? s_cdf[tid - st] : 0.0;
                __syncthreads();
                if (tid < 512) s_cdf[tid] += v;
                __syncthreads();
            }
            if (tid == 0) s_red[9] = 1.0 / s_cdf[n - 1];
            __syncthreads();
            if (tid < n) {
                double il = s_red[9], u = s_red[10];
                double right = s_cdf[tid] * il;
                double left  = tid ? s_cdf[tid - 1] * il : 0.0;
                if (right > u && left <= u) s_int[14] = tid;   // searchsorted 'right'
            }
            __syncthreads();
            if (!dbuf) BAR();   // single-buffer: protect d2 from next publish
            s_cent[j * DD + tid] = F[(size_t)s_int[14] * DD + tid];
            __syncthreads();
        }
        // ---- tiled slice pass: d2 vs center j (+ proto partials on j==0) ----
        float4 cj[3];
        #pragma unroll
        for (int i = 0; i < 3; ++i) cj[i] = *(const float4*)(s_cent + j * DD + 4 * ln + 256 * i);

        float4 stg[4];
        if (ntl > 0) {
            size_t base = (size_t)p0g * DD;
            #pragma unroll
            for (int q = 0; q < 4; ++q) stg[q] = *(const float4*)(F + base + 4 * (tid + NT * q));
            #pragma unroll
            for (int q = 0; q < 4; ++q) {
                int c = tid + NT * q;
                *(float4*)(s_tile + (c / 192) * DD + 4 * (c % 192)) = stg[q];
            }
        }
        __syncthreads();
        for (int t = 0; t < ntl; ++t) {
            const int cur = t & 1, nxt = cur ^ 1;
            const float* tb = s_tile + cur * (TILE_P * DD);
            if (t + 1 < ntl) {
                size_t base = (size_t)(p0g + (t + 1) * TILE_P) * DD;
                #pragma unroll
                for (int q = 0; q < 4; ++q) stg[q] = *(const float4*)(F + base + 4 * (tid + NT * q));
            }
            for (int pl = wv; pl < TILE_P; pl += NWAVES) {
                int lp = t * TILE_P + pl;
                if (lp < nb) {
                    const float* row = tb + pl * DD;
                    float a = 0.f;
                    #pragma unroll
                    for (int i = 0; i < 3; ++i) {
                        float4 x = *(const float4*)(row + 4 * ln + 256 * i);
                        float d;
                        d = x.x - cj[i].x; a = fmaf(d, d, a);
                        d = x.y - cj[i].y; a = fmaf(d, d, a);
                        d = x.z - cj[i].z; a = fmaf(d, d, a);
                        d = x.w - cj[i].w; a = fmaf(d, d, a);
                    }
                    a = wsum64(a);
                    if (ln == 0) s_d2[lp] = (j == 0) ? a : fminf(s_d2[lp], a);
                }
            }
            if (j == 0) {
                const uint4 lw4 = *(const uint4*)(s_lab + p0g + t * 16);
                const unsigned lw0 = lw4.x, lw1 = lw4.y, lw2 = lw4.z, lw3 = lw4.w;
                const int m = min(TILE_P, nb - t * TILE_P);
                #pragma unroll
                for (int i = 0; i < TILE_P; ++i) {
                    if (i < m) {
                        unsigned w = (i < 4) ? lw0 : (i < 8) ? lw1 : (i < 12) ? lw2 : lw3;
                        int l = (w >> ((i & 3) * 8)) & 255;
                        float x = tb[i * DD + tid];
                        switch (l) {
                            case 0: pp0 += x; break;
                            case 1: pp1 += x; break;
                            case 2: pp2 += x; break;
                            default: pp3 += x;
                        }
                    }
                }
            }
            if (t + 1 < ntl) {
                #pragma unroll
                for (int q = 0; q < 4; ++q) {
                    int c = tid + NT * q;
                    *(float4*)(s_tile + nxt * (TILE_P * DD) + (c / 192) * DD + 4 * (c % 192)) = stg[q];
                }
            }
            __syncthreads();
        }
        if (j == 0) {
            size_t pb = (((size_t)bi * NSUB + sub) * 4) * DD + tid;
            ustoref(&g_pp[pb + 0 * DD], (float)pp0);
            ustoref(&g_pp[pb + 1 * DD], (float)pp1);
            ustoref(&g_pp[pb + 2 * DD], (float)pp2);
            ustoref(&g_pp[pb + 3 * DD], (float)pp3);
        }
        if (j < kk - 1) {
            const int pj = dbuf ? (j & 1) : 0;
            if (tid < nb) ustoref(&g_d2[(size_t)pj * D2_HALF + bi * TT + p0g + tid], s_d2[tid]);
            BAR();
        }
    }

    // ================= Lloyd iterations (1 barrier/iter when dbuf) ========
    for (int it = 0; it < KM_ITERS; ++it) {
        const int pi = dbuf ? (it & 1) : 0;
        float4 creg[6][3];
        #pragma unroll
        for (int c = 0; c < 6; ++c)
            #pragma unroll
            for (int i = 0; i < 3; ++i)
                creg[c][i] = *(const float4*)(s_cent + c * DD + 4 * ln + 256 * i);
        if (tid < 8) s_int[tid] = 0;
        double u0 = 0, u1 = 0, u2 = 0, u3 = 0, u4 = 0, u5 = 0;

        float4 stg[4];
        if (ntl > 0) {
            size_t base = (size_t)p0g * DD;
            #pragma unroll
            for (int q = 0; q < 4; ++q) stg[q] = *(const float4*)(F + base + 4 * (tid + NT * q));
            #pragma unroll
            for (int q = 0; q < 4; ++q) {
                int c = tid + NT * q;
                *(float4*)(s_tile + (c / 192) * DD + 4 * (c % 192)) = stg[q];
            }
        }
        __syncthreads();

        for (int t = 0; t < ntl; ++t) {
            const int cur = t & 1, nxt = cur ^ 1;
            const float* tb = s_tile + cur * (TILE_P * DD);
            if (t + 1 < ntl) {
                size_t base = (size_t)(p0g + (t + 1) * TILE_P) * DD;
                #pragma unroll
                for (int q = 0; q < 4; ++q) stg[q] = *(const float4*)(F + base + 4 * (tid + NT * q));
            }
            // ---- ASSIGN ----
            for (int pl = wv; pl < TILE_P; pl += NWAVES) {
                int lp = t * TILE_P + pl;
                if (lp < nb) {
                    const float* row = tb + pl * DD;
                    float a0 = 0, a1 = 0, a2 = 0, a3 = 0, a4 = 0, a5 = 0;
                    #pragma unroll
                    for (int i = 0; i < 3; ++i) {
                        float4 x = *(const float4*)(row + 4 * ln + 256 * i);
                        float d;
                        d = x.x - creg[0][i].x; a0 = fmaf(d, d, a0);
                        d = x.y - creg[0][i].y; a0 = fmaf(d, d, a0);
                        d = x.z - creg[0][i].z; a0 = fmaf(d, d, a0);
                        d = x.w - creg[0][i].w; a0 = fmaf(d, d, a0);
                        d = x.x - creg[1][i].x; a1 = fmaf(d, d, a1);
                        d = x.y - creg[1][i].y; a1 = fmaf(d, d, a1);
                        d = x.z - creg[1][i].z; a1 = fmaf(d, d, a1);
                        d = x.w - creg[1][i].w; a1 = fmaf(d, d, a1);
                        d = x.x - creg[2][i].x; a2 = fmaf(d, d, a2);
                        d = x.y - creg[2][i].y; a2 = fmaf(d, d, a2);
                        d = x.z - creg[2][i].z; a2 = fmaf(d, d, a2);
                        d = x.w - creg[2][i].w; a2 = fmaf(d, d, a2);
                        d = x.x - creg[3][i].x; a3 = fmaf(d, d, a3);
                        d = x.y - creg[3][i].y; a3 = fmaf(d, d, a3);
                        d = x.z - creg[3][i].z; a3 = fmaf(d, d, a3);
                        d = x.w - creg[3][i].w; a3 = fmaf(d, d, a3);
                        d = x.x - creg[4][i].x; a4 = fmaf(d, d, a4);
                        d = x.y - creg[4][i].y; a4 = fmaf(d, d, a4);
                        d = x.z - creg[4][i].z; a4 = fmaf(d, d, a4);
                        d = x.w - creg[4][i].w; a4 = fmaf(d, d, a4);
                        d = x.x - creg[5][i].x; a5 = fmaf(d, d, a5);
                        d = x.y - creg[5][i].y; a5 = fmaf(d, d, a5);
                        d = x.z - creg[5][i].z; a5 = fmaf(d, d, a5);
                        d = x.w - creg[5][i].w; a5 = fmaf(d, d, a5);
                    }
                    a0 = wsum64(a0); a1 = wsum64(a1); a2 = wsum64(a2);
                    a3 = wsum64(a3); a4 = wsum64(a4); a5 = wsum64(a5);
                    int bj = 0; float bv = a0;
                    if (kk > 1 && a1 < bv) { bv = a1; bj = 1; }
                    if (kk > 2 && a2 < bv) { bv = a2; bj = 2; }
                    if (kk > 3 && a3 < bv) { bv = a3; bj = 3; }
                    if (kk > 4 && a4 < bv) { bv = a4; bj = 4; }
                    if (kk > 5 && a5 < bv) { bv = a5; bj = 5; }
                    if (ln == 0) { s_asn[lp] = (unsigned char)bj; atomicAdd(&s_int[bj], 1); }
                }
            }
            __syncthreads();
            if (t + 1 < ntl) {
                #pragma unroll
                for (int q = 0; q < 4; ++q) {
                    int c = tid + NT * q;
                    *(float4*)(s_tile + nxt * (TILE_P * DD) + (c / 192) * DD + 4 * (c % 192)) = stg[q];
                }
            }
            // ---- UPDATE (dim-owner) ----
            {
                const uint4 aw4 = *(const uint4*)(s_asn + t * 16);
                const unsigned aw0 = aw4.x, aw1 = aw4.y, aw2 = aw4.z, aw3 = aw4.w;
                const int m = min(TILE_P, nb - t * TILE_P);
                #pragma unroll
                for (int i = 0; i < TILE_P; ++i) {
                    if (i < m) {
                        unsigned w = (i < 4) ? aw0 : (i < 8) ? aw1 : (i < 12) ? aw2 : aw3;
                        int c = (w >> ((i & 3) * 8)) & 255;
                        float x = tb[i * DD + tid];
                        switch (c) {
                            case 0: u0 += x; break;
                            case 1: u1 += x; break;
                            case 2: u2 += x; break;
                            case 3: u3 += x; break;
                            case 4: u4 += x; break;
                            default: u5 += x;
                        }
                    }
                }
            }
            __syncthreads();
        }
        // publish partials (uncached)
        {
            size_t pb = (size_t)pi * PS_HALF + (((size_t)bi * NSUB + sub) * 6) * DD + tid;
            ustoref(&g_ps[pb + 0 * DD], (float)u0);
            ustoref(&g_ps[pb + 1 * DD], (float)u1);
            ustoref(&g_ps[pb + 2 * DD], (float)u2);
            ustoref(&g_ps[pb + 3 * DD], (float)u3);
            ustoref(&g_ps[pb + 4 * DD], (float)u4);
            ustoref(&g_ps[pb + 5 * DD], (float)u5);
        }
        if (tid < 8)
            ustorei(&g_cnt[(size_t)pi * CNT_HALF + ((size_t)bi * NSUB + sub) * 8 + tid], s_int[tid]);
        BAR();   // all partials for iter `it` at coherence point
        if (tid < 32)
            s_int[32 + tid] = uloadi(&g_cnt[(size_t)pi * CNT_HALF + ((size_t)bi * NSUB + (tid >> 3)) * 8 + (tid & 7)]);
        __syncthreads();
        #pragma unroll
        for (int c = 0; c < 6; ++c) {
            int cc = s_int[32 + c] + s_int[40 + c] + s_int[48 + c] + s_int[56 + c];
            size_t pb = (size_t)pi * PS_HALF + ((size_t)bi * NSUB * 6 + c) * DD + tid;
            double sv = (double)uloadf(&g_ps[pb])
                      + (double)uloadf(&g_ps[pb + 6 * DD])
                      + (double)uloadf(&g_ps[pb + 12 * DD])
                      + (double)uloadf(&g_ps[pb + 18 * DD]);
            if (cc > 0) s_cent[c * DD + tid] = (float)(sv / (double)cc);
        }
        __syncthreads();
        if (!dbuf) BAR();   // single-buffer fallback: protect before overwrite
    }

    // ================= epilogue (sub 0 only) =================
    if (sub == 0) {
        #pragma unroll
        for (int l = 0; l < 4; ++l) {
            size_t pb = ((size_t)bi * NSUB * 4 + l) * DD + tid;
            double sv = (double)uloadf(&g_pp[pb])
                      + (double)uloadf(&g_pp[pb + 4 * DD])
                      + (double)uloadf(&g_pp[pb + 8 * DD])
                      + (double)uloadf(&g_pp[pb + 12 * DD]);
            s_proto[l * DD + tid] = (float)(sv / (double)s_int[8 + l]);
        }
        __syncthreads();
        for (int pr = wv; pr < lr * kk; pr += NWAVES) {
            int r = pr / kk, c = pr - (pr / kk) * kk;
            double acc = 0.0;
            #pragma unroll
            for (int i = 0; i < 12; ++i) {
                int d = ln + 64 * i;
                double df = (double)s_proto[r * DD + d] - (double)s_cent[c * DD + d];
                acc += df * df;
            }
            acc = dsum64(acc);
            if (ln == 0) s_cost[r * KMAX + c] = sqrt(acc);
        }
        __syncthreads();
        if (tid == 0) {
            const int sdim = (lr <= kk) ? lr : kk;
            const int mdim = (lr <= kk) ? kk : lr;
            const bool tr = (lr > kk);
            auto CC = [&](int i, int j) -> double {
                return tr ? s_cost[j * KMAX + i] : s_cost[i * KMAX + j];
            };
            double best = 1e300;
            for (int c0 = 0; c0 < mdim; ++c0) {
                double v0 = CC(0, c0);
                if (sdim == 1) { if (v0 < best) best = v0; continue; }
                for (int c1 = 0; c1 < mdim; ++c1) {
                    if (c1 == c0) continue;
                    double v1 = v0 + CC(1, c1);
                    if (sdim == 2) { if (v1 < best) best = v1; continue; }
                    for (int c2 = 0; c2 < mdim; ++c2) {
                        if (c2 == c0 || c2 == c1) continue;
                        double v2 = v1 + CC(2, c2);
                        if (sdim == 3) { if (v2 < best) best = v2; continue; }
                        for (int c3 = 0; c3 < mdim; ++c3) {
                            if (c3 == c0 || c3 == c1 || c3 == c2) continue;
                            double v3 = v2 + CC(3, c3);
                            if (v3 < best) best = v3;
                        }
                    }
                }
            }
            double meand = best / (double)sdim;
            double kp = (double)kprob[bi * KMAX + (lr - 1)];
            g_loss[bi] = (float)(0.5 * meand - 0.5 * log(kp));
        }
    }
}

__global__ void pkd_reduce(const float* __restrict__ losses, float* __restrict__ out) {
    if (blockIdx.x == 0 && threadIdx.x == 0) {
        double s = 0.0;
        for (int i = 0; i < BB; ++i) s += (double)losses[i];
        out[0] = (float)(s / (double)BB);
    }
}

extern "C" void kernel_launch(void* const* d_in, const int* in_sizes, int n_in,
                              void* d_out, int out_size, void* d_ws, size_t ws_size,
                              hipStream_t stream) {
    const float* feats  = (const float*)d_in[0];
    const int*   dlens  = (const int*)d_in[1];
    const int*   labels = (const int*)d_in[2];
    const float* kprob  = (const float*)d_in[3];
    char* wsp = (char*)d_ws;
    int dbuf = (ws_size >= WS_END_DBUF) ? 1 : 0;

    hipMemsetAsync(d_ws, 0, 4096, stream);   // zero barrier counters
    (void)hipFuncSetAttribute((const void*)pkd_main,
                              hipFuncAttributeMaxDynamicSharedMemorySize, SMEM_BYTES);
    void* args[6] = {(void*)&feats, (void*)&dlens, (void*)&labels,
                     (void*)&kprob, (void*)&wsp, (void*)&dbuf};
    hipLaunchCooperativeKernel((const void*)pkd_main, dim3(BB * NSUB), dim3(NT),
                               args, SMEM_BYTES, stream);
    pkd_reduce<<<1, 64, 0, stream>>>((const float*)(wsp + WS_LOSS), (float*)d_out);
}